// Round 1
// 372.868 us; speedup vs baseline: 1.0005x; 1.0005x over previous
//
#include <hip/hip_runtime.h>
#include <hip/hip_bf16.h>

#define BSZ 128
#define NN  4000
#define DD  128
#define NB  10
#define SEQ 400

typedef __attribute__((ext_vector_type(8)))  short short8;
typedef __attribute__((ext_vector_type(16))) float f32x16;

// ---- prep: swizzle conv1_w into exact B-fragment order for v_mfma_f32_32x32x16_bf16
// Bfrag[ks][t][lane][j], K-assignment per wave ks (K=320 each):
//   t 0-7   -> neighbor 2ks,   d = t*16 + kin
//   t 8-15  -> neighbor 2ks+1, d = (t-8)*16 + kin
//   t 16-19 -> neighbor 8+(ks>>1), d = (ks&1)*64 + (t-16)*16 + kin
// kin = (lane>>5)*8 + j  (B: n=lane&31, k=kin)
__global__ void pscn_prep(const float* __restrict__ w1, unsigned short* __restrict__ bf) {
    int id = blockIdx.x * 256 + threadIdx.x;
    if (id >= 40960) return;
    int j   = id & 7;
    int l   = (id >> 3) & 63;
    int rem = id >> 9;            // ks*20 + t
    int t   = rem % 20;
    int ks  = rem / 20;
    int kin = ((l >> 5) << 3) + j;
    int kk, d;
    if (t < 8)       { kk = 2 * ks;         d = t * 16 + kin; }
    else if (t < 16) { kk = 2 * ks + 1;     d = (t - 8) * 16 + kin; }
    else             { kk = 8 + (ks >> 1);  d = (ks & 1) * 64 + (t - 16) * 16 + kin; }
    int c1 = l & 31;
    float v = w1[c1 * (DD * NB) + d * NB + kk];
    union { __hip_bfloat16 h; unsigned short u; } cv;
    cv.h = __float2bfloat16(v);
    bf[id] = cv.u;
}

__global__ void pscn_init_out(const float* __restrict__ fc_b, float* __restrict__ out) {
    if (threadIdx.x < BSZ) out[threadIdx.x] = fc_b[0];
}

__device__ inline short8 cvt8(float4 lo, float4 hi) {
    union { __hip_bfloat162 h[4]; short8 s; } u;
    u.h[0] = __float22bfloat162_rn(make_float2(lo.x, lo.y));
    u.h[1] = __float22bfloat162_rn(make_float2(lo.z, lo.w));
    u.h[2] = __float22bfloat162_rn(make_float2(hi.x, hi.y));
    u.h[3] = __float22bfloat162_rn(make_float2(hi.z, hi.w));
    return u.s;
}

// block = 256 thr = 4 waves = 4-way K-split; block covers 32 positions; grid = 1600
// launch_bounds (256,4): 128-VGPR cap -> no scratch spill (R3's (256,5)=102 cap was
// the suspected spill trigger); actual use ~90 -> 5 waves/SIMD.
__global__ __launch_bounds__(256, 4) void pscn_main(
    const int*   __restrict__ recep,
    const float* __restrict__ nf,
    const short8* __restrict__ bfrag,
    const float* __restrict__ b1,
    const float* __restrict__ w2,
    const float* __restrict__ cb2,
    const float* __restrict__ fcw,
    float*       __restrict__ out)
{
    __shared__ float cred[3][32][33];   // K-split partials, conflict-free (stride 33)
    __shared__ float y1s[32][33];       // [c1][pos]
    __shared__ float w2s[1024];         // w2s[c1*32+c2]
    __shared__ float contrib[32];

    // XCD-aware swizzle (T1): hw wg i lands on XCD i%8 (round-robin dispatch).
    // 1600 = 8*200 exactly -> bijective: logical = (hw&7)*200 + (hw>>3).
    // XCD x then owns logical blocks [200x,200x+200) = graphs [16x,16x+16);
    // each graph's 2 MB feature slab fits the XCD-private 4 MB L2, so the
    // ~1.58x intrinsic row-reuse (4000 draws of 4000 rows) becomes L2 hits
    // instead of 8-way-replicated HBM re-fetches.
    const int bid = (blockIdx.x & 7) * 200 + (blockIdx.x >> 3);

    const int tid  = threadIdx.x;
    const int lane = tid & 63;
    const int wv   = __builtin_amdgcn_readfirstlane(tid >> 6);
    const int ks   = wv;                // K-split id 0..3
    const int m    = lane & 31;         // position (MFMA A: m=lane&31)
    const int half = lane >> 5;         // k-half   (MFMA A: k=half*8+j)

    for (int i = tid; i < 1024; i += 256) {
        int c1 = i >> 5, c2 = i & 31;
        w2s[c1 * 32 + c2] = w2[c2 * 32 + c1];
    }

    const int sid = bid * 32 + m;
    const int b   = sid / SEQ;
    const int sp  = sid - b * SEQ;

    const int* rr = recep + b * NN + sp * NB;
    const int idxA = rr[2 * ks];
    const int idxB = rr[2 * ks + 1];
    const int idxC = rr[8 + (ks >> 1)];

    const float* rp[3];
    rp[0] = nf + ((size_t)b * NN + idxA) * DD + half * 8;
    rp[1] = nf + ((size_t)b * NN + idxB) * DD + half * 8;
    rp[2] = nf + ((size_t)b * NN + idxC) * DD + (ks & 1) * 64 + half * 8;

    f32x16 C;
#pragma unroll
    for (int i = 0; i < 16; ++i) C[i] = 0.f;

    const short8* bp = bfrag + ks * 20 * 64 + lane;

    // software pipeline: 20 single-MFMA steps, prefetch depth 3, 4 rotating slots
    float4 Ab[4][2];
    short8 Bb[4];
#pragma unroll
    for (int t = 0; t < 3; ++t) {
        const float* p = rp[t >> 3] + (t & 7) * 16;
        Ab[t][0] = ((const float4*)p)[0];
        Ab[t][1] = ((const float4*)p)[1];
        Bb[t]    = bp[t * 64];
    }
#pragma unroll
    for (int t = 0; t < 20; ++t) {
        if (t + 3 < 20) {
            const int tn = t + 3;                 // compile-time after unroll
            const int sl = tn & 3;
            const float* p = rp[tn >> 3] + (tn & 7) * 16;
            Ab[sl][0] = ((const float4*)p)[0];
            Ab[sl][1] = ((const float4*)p)[1];
            Bb[sl]    = bp[tn * 64];
        }
        const int sc = t & 3;
        short8 a = cvt8(Ab[sc][0], Ab[sc][1]);
        C = __builtin_amdgcn_mfma_f32_32x32x16_bf16(a, Bb[sc], C, 0, 0, 0);
    }

    // reduce K-split partials; C/D: col(c1)=lane&31, row(p)=(r&3)+8*(r>>2)+4*half
    if (ks > 0) {
#pragma unroll
        for (int r = 0; r < 16; ++r) {
            int p = (r & 3) + 8 * (r >> 2) + 4 * half;
            cred[ks - 1][p][m] = C[r];
        }
    }
    __syncthreads();
    if (ks == 0) {
        float bv = b1[m];
#pragma unroll
        for (int r = 0; r < 16; ++r) {
            int p = (r & 3) + 8 * (r >> 2) + 4 * half;
            float v = C[r] + cred[0][p][m] + cred[1][p][m] + cred[2][p][m] + bv;
            y1s[m][p] = fmaxf(v, 0.f);
        }
    }
    __syncthreads();

    // conv2 (1x1) + relu + fc partial: thread = (s_l = tid>>3, oc = tid&7), 4 c2 each
    {
        const int s_l  = tid >> 3;
        const int oc   = tid & 7;
        const int sid2 = bid * 32 + s_l;
        const int bb   = sid2 / SEQ;
        const int sp2  = sid2 - bb * SEQ;
        float val = 0.f;
#pragma unroll
        for (int j = 0; j < 4; ++j) {
            const int c2 = oc * 4 + j;
            float y2 = cb2[c2];
#pragma unroll
            for (int c1 = 0; c1 < 32; ++c1)
                y2 += y1s[c1][s_l] * w2s[c1 * 32 + c2];
            y2 = fmaxf(y2, 0.f);
            val += y2 * fcw[c2 * SEQ + sp2];
        }
        val += __shfl_xor(val, 1);
        val += __shfl_xor(val, 2);
        val += __shfl_xor(val, 4);
        if (oc == 0) contrib[s_l] = val;
    }
    __syncthreads();

    // block reduce (<=2 distinct graphs per 32-pos block) + atomicAdd
    if (wv == 0) {
        float v = (lane < 32) ? contrib[lane] : 0.f;
        const int bl     = (bid * 32 + (lane & 31)) / SEQ;
        const int bfirst = (bid * 32) / SEQ;
        const int blast  = (bid * 32 + 31) / SEQ;
        for (int tb = bfirst; tb <= blast; ++tb) {
            float r = (bl == tb && lane < 32) ? v : 0.f;
#pragma unroll
            for (int off = 1; off < 64; off <<= 1) r += __shfl_xor(r, off);
            if (lane == 0) atomicAdd(&out[tb], r);
        }
    }
}

extern "C" void kernel_launch(void* const* d_in, const int* in_sizes, int n_in,
                              void* d_out, int out_size, void* d_ws, size_t ws_size,
                              hipStream_t stream) {
    const int*   recep = (const int*)  d_in[0];
    const float* nfeat = (const float*)d_in[1];
    const float* w1    = (const float*)d_in[2];
    const float* b1    = (const float*)d_in[3];
    const float* w2    = (const float*)d_in[4];
    const float* cb2   = (const float*)d_in[5];
    const float* fcw   = (const float*)d_in[6];
    const float* fcb   = (const float*)d_in[7];
    float* outp = (float*)d_out;
    unsigned short* bfrag = (unsigned short*)d_ws;   // 40960 bf16 = 80 KB

    pscn_prep<<<160, 256, 0, stream>>>(w1, bfrag);
    pscn_init_out<<<1, 128, 0, stream>>>(fcb, outp);
    pscn_main<<<(BSZ * SEQ) / 32, 256, 0, stream>>>(
        recep, nfeat, (const short8*)d_ws, b1, w2, cb2, fcw, outp);
}

// Round 2
// 372.198 us; speedup vs baseline: 1.0023x; 1.0018x over previous
//
#include <hip/hip_runtime.h>
#include <hip/hip_bf16.h>

#define BSZ 128
#define NN  4000
#define DD  128
#define NB  10
#define SEQ 400

typedef __attribute__((ext_vector_type(8)))  short short8;
typedef __attribute__((ext_vector_type(16))) float f32x16;

// ---- prep: swizzle conv1_w into exact B-fragment order for v_mfma_f32_32x32x16_bf16
// Bfrag[ks][t][lane][j], K-assignment per wave ks (K=320 each):
//   t 0-7   -> neighbor 2ks,   d = t*16 + kin
//   t 8-15  -> neighbor 2ks+1, d = (t-8)*16 + kin
//   t 16-19 -> neighbor 8+(ks>>1), d = (ks&1)*64 + (t-16)*16 + kin
// kin = (lane>>5)*8 + j  (B: n=lane&31, k=kin)
// Block 0 additionally initializes out[] = fc_b (was a separate 1-block kernel;
// folding it here removes one graph node + serialization edge, ~2-4 us).
__global__ void pscn_prep(const float* __restrict__ w1, unsigned short* __restrict__ bf,
                          const float* __restrict__ fc_b, float* __restrict__ out) {
    if (blockIdx.x == 0 && threadIdx.x < BSZ) out[threadIdx.x] = fc_b[0];
    int id = blockIdx.x * 256 + threadIdx.x;
    if (id >= 40960) return;
    int j   = id & 7;
    int l   = (id >> 3) & 63;
    int rem = id >> 9;            // ks*20 + t
    int t   = rem % 20;
    int ks  = rem / 20;
    int kin = ((l >> 5) << 3) + j;
    int kk, d;
    if (t < 8)       { kk = 2 * ks;         d = t * 16 + kin; }
    else if (t < 16) { kk = 2 * ks + 1;     d = (t - 8) * 16 + kin; }
    else             { kk = 8 + (ks >> 1);  d = (ks & 1) * 64 + (t - 16) * 16 + kin; }
    int c1 = l & 31;
    float v = w1[c1 * (DD * NB) + d * NB + kk];
    union { __hip_bfloat16 h; unsigned short u; } cv;
    cv.h = __float2bfloat16(v);
    bf[id] = cv.u;
}

__device__ inline short8 cvt8(float4 lo, float4 hi) {
    union { __hip_bfloat162 h[4]; short8 s; } u;
    u.h[0] = __float22bfloat162_rn(make_float2(lo.x, lo.y));
    u.h[1] = __float22bfloat162_rn(make_float2(lo.z, lo.w));
    u.h[2] = __float22bfloat162_rn(make_float2(hi.x, hi.y));
    u.h[3] = __float22bfloat162_rn(make_float2(hi.z, hi.w));
    return u.s;
}

// block = 256 thr = 4 waves = 4-way K-split; block covers 32 positions; grid = 1600
// launch_bounds (256,4): 128-VGPR cap -> no scratch spill; actual use ~90 -> 5 waves/SIMD.
// HBM-bound: 262 MB gather at ~88% of stream ceiling; latency fully covered by
// ~180 KB in-flight/CU. Swizzle (R0) measured neutral, kept as harmless.
__global__ __launch_bounds__(256, 4) void pscn_main(
    const int*   __restrict__ recep,
    const float* __restrict__ nf,
    const short8* __restrict__ bfrag,
    const float* __restrict__ b1,
    const float* __restrict__ w2,
    const float* __restrict__ cb2,
    const float* __restrict__ fcw,
    float*       __restrict__ out)
{
    __shared__ float cred[3][32][33];   // K-split partials, conflict-free (stride 33)
    __shared__ float y1s[32][33];       // [c1][pos]
    __shared__ float w2s[1024];         // w2s[c1*32+c2]
    __shared__ float contrib[32];

    // XCD-aware swizzle (T1): bijective since 1600 = 8*200.
    const int bid = (blockIdx.x & 7) * 200 + (blockIdx.x >> 3);

    const int tid  = threadIdx.x;
    const int lane = tid & 63;
    const int wv   = __builtin_amdgcn_readfirstlane(tid >> 6);
    const int ks   = wv;                // K-split id 0..3
    const int m    = lane & 31;         // position (MFMA A: m=lane&31)
    const int half = lane >> 5;         // k-half   (MFMA A: k=half*8+j)

    for (int i = tid; i < 1024; i += 256) {
        int c1 = i >> 5, c2 = i & 31;
        w2s[c1 * 32 + c2] = w2[c2 * 32 + c1];
    }

    const int sid = bid * 32 + m;
    const int b   = sid / SEQ;
    const int sp  = sid - b * SEQ;

    const int* rr = recep + b * NN + sp * NB;
    const int idxA = rr[2 * ks];
    const int idxB = rr[2 * ks + 1];
    const int idxC = rr[8 + (ks >> 1)];

    const float* rp[3];
    rp[0] = nf + ((size_t)b * NN + idxA) * DD + half * 8;
    rp[1] = nf + ((size_t)b * NN + idxB) * DD + half * 8;
    rp[2] = nf + ((size_t)b * NN + idxC) * DD + (ks & 1) * 64 + half * 8;

    f32x16 C;
#pragma unroll
    for (int i = 0; i < 16; ++i) C[i] = 0.f;

    const short8* bp = bfrag + ks * 20 * 64 + lane;

    // software pipeline: 20 single-MFMA steps, prefetch depth 3, 4 rotating slots
    float4 Ab[4][2];
    short8 Bb[4];
#pragma unroll
    for (int t = 0; t < 3; ++t) {
        const float* p = rp[t >> 3] + (t & 7) * 16;
        Ab[t][0] = ((const float4*)p)[0];
        Ab[t][1] = ((const float4*)p)[1];
        Bb[t]    = bp[t * 64];
    }
#pragma unroll
    for (int t = 0; t < 20; ++t) {
        if (t + 3 < 20) {
            const int tn = t + 3;                 // compile-time after unroll
            const int sl = tn & 3;
            const float* p = rp[tn >> 3] + (tn & 7) * 16;
            Ab[sl][0] = ((const float4*)p)[0];
            Ab[sl][1] = ((const float4*)p)[1];
            Bb[sl]    = bp[tn * 64];
        }
        const int sc = t & 3;
        short8 a = cvt8(Ab[sc][0], Ab[sc][1]);
        C = __builtin_amdgcn_mfma_f32_32x32x16_bf16(a, Bb[sc], C, 0, 0, 0);
    }

    // reduce K-split partials; C/D: col(c1)=lane&31, row(p)=(r&3)+8*(r>>2)+4*half
    if (ks > 0) {
#pragma unroll
        for (int r = 0; r < 16; ++r) {
            int p = (r & 3) + 8 * (r >> 2) + 4 * half;
            cred[ks - 1][p][m] = C[r];
        }
    }
    __syncthreads();
    if (ks == 0) {
        float bv = b1[m];
#pragma unroll
        for (int r = 0; r < 16; ++r) {
            int p = (r & 3) + 8 * (r >> 2) + 4 * half;
            float v = C[r] + cred[0][p][m] + cred[1][p][m] + cred[2][p][m] + bv;
            y1s[m][p] = fmaxf(v, 0.f);
        }
    }
    __syncthreads();

    // conv2 (1x1) + relu + fc partial: thread = (s_l = tid>>3, oc = tid&7), 4 c2 each
    {
        const int s_l  = tid >> 3;
        const int oc   = tid & 7;
        const int sid2 = bid * 32 + s_l;
        const int bb   = sid2 / SEQ;
        const int sp2  = sid2 - bb * SEQ;
        float val = 0.f;
#pragma unroll
        for (int j = 0; j < 4; ++j) {
            const int c2 = oc * 4 + j;
            float y2 = cb2[c2];
#pragma unroll
            for (int c1 = 0; c1 < 32; ++c1)
                y2 += y1s[c1][s_l] * w2s[c1 * 32 + c2];
            y2 = fmaxf(y2, 0.f);
            val += y2 * fcw[c2 * SEQ + sp2];
        }
        val += __shfl_xor(val, 1);
        val += __shfl_xor(val, 2);
        val += __shfl_xor(val, 4);
        if (oc == 0) contrib[s_l] = val;
    }
    __syncthreads();

    // block reduce (<=2 distinct graphs per 32-pos block) + atomicAdd
    if (wv == 0) {
        float v = (lane < 32) ? contrib[lane] : 0.f;
        const int bl     = (bid * 32 + (lane & 31)) / SEQ;
        const int bfirst = (bid * 32) / SEQ;
        const int blast  = (bid * 32 + 31) / SEQ;
        for (int tb = bfirst; tb <= blast; ++tb) {
            float r = (bl == tb && lane < 32) ? v : 0.f;
#pragma unroll
            for (int off = 1; off < 64; off <<= 1) r += __shfl_xor(r, off);
            if (lane == 0) atomicAdd(&out[tb], r);
        }
    }
}

extern "C" void kernel_launch(void* const* d_in, const int* in_sizes, int n_in,
                              void* d_out, int out_size, void* d_ws, size_t ws_size,
                              hipStream_t stream) {
    const int*   recep = (const int*)  d_in[0];
    const float* nfeat = (const float*)d_in[1];
    const float* w1    = (const float*)d_in[2];
    const float* b1    = (const float*)d_in[3];
    const float* w2    = (const float*)d_in[4];
    const float* cb2   = (const float*)d_in[5];
    const float* fcw   = (const float*)d_in[6];
    const float* fcb   = (const float*)d_in[7];
    float* outp = (float*)d_out;
    unsigned short* bfrag = (unsigned short*)d_ws;   // 40960 bf16 = 80 KB

    pscn_prep<<<160, 256, 0, stream>>>(w1, bfrag, fcb, outp);
    pscn_main<<<(BSZ * SEQ) / 32, 256, 0, stream>>>(
        recep, nfeat, (const short8*)d_ws, b1, w2, cb2, fcw, outp);
}